// Round 23
// baseline (135.250 us; speedup 1.0000x reference)
//
#include <hip/hip_runtime.h>
#include <cstdint>

#define B_ 2
#define N_ 2048
#define C_ 1024
#define H_ 16
#define D_ 64
#define M_TOT 4096
#define QKV_N 3072
#define BH_ 32
static constexpr float SCALE = 0.125f;            // 64^-0.5
static constexpr float LOG2E = 1.44269504088896f;
static constexpr float QSCALE = SCALE * LOG2E;    // baked into stored q

typedef __attribute__((ext_vector_type(8))) _Float16 half8;   // 4 VGPR
typedef __attribute__((ext_vector_type(4))) _Float16 half4v;
typedef __attribute__((ext_vector_type(2))) __fp16 fp16x2;
typedef __attribute__((ext_vector_type(4))) float f32x4;
typedef __attribute__((ext_vector_type(16))) float f32x16;

#define MFMAH(a, b, c)  __builtin_amdgcn_mfma_f32_16x16x32_f16((a), (b), (c), 0, 0, 0)
#define MFMA32(a, b, c) __builtin_amdgcn_mfma_f32_32x32x16_f16((a), (b), (c), 0, 0, 0)

__device__ inline void gl16(const void* g, void* l) {
    __builtin_amdgcn_global_load_lds(
        (const __attribute__((address_space(1))) unsigned int*)g,
        (__attribute__((address_space(3))) unsigned int*)l, 16, 0, 0);
}

__device__ inline unsigned pk2(float a, float b) {
    fp16x2 t = __builtin_amdgcn_cvt_pkrtz(a, b);
    return __builtin_bit_cast(unsigned, t);
}

// ---------------------------------------------------------------------------
// Merged pre-pass (one launch)
// ---------------------------------------------------------------------------
__global__ __launch_bounds__(256) void prep_kernel(
    const float* __restrict__ x, const float* __restrict__ w_qkv,
    const float* __restrict__ w_proj,
    _Float16* __restrict__ xh, _Float16* __restrict__ wqT,
    _Float16* __restrict__ wpT)
{
    const int bid = blockIdx.x, tid = threadIdx.x;
    if (bid < 2048) {
        #pragma unroll
        for (int e = 0; e < 2; ++e) {
            const int i = bid * 256 + tid + e * 524288;
            const float4 v = ((const float4*)x)[i];
            half4v h;
            h.x = (_Float16)v.x; h.y = (_Float16)v.y;
            h.z = (_Float16)v.z; h.w = (_Float16)v.w;
            ((half4v*)xh)[i] = h;
        }
        return;
    }
    __shared__ float t[32][33];
    const float* src;
    _Float16* dst;
    int Ncols, n0, k0;
    if (bid < 5120) {
        const int b = bid - 2048;
        src = w_qkv; dst = wqT; Ncols = QKV_N;
        n0 = (b % 96) * 32; k0 = (b / 96) * 32;
    } else {
        const int b = bid - 5120;
        src = w_proj; dst = wpT; Ncols = C_;
        n0 = (b & 31) * 32; k0 = (b >> 5) * 32;
    }
    {
        const int r = tid >> 3, c4 = (tid & 7) * 4;
        const float4 v = *(const float4*)&src[(size_t)(k0 + r) * Ncols + n0 + c4];
        t[r][c4+0] = v.x; t[r][c4+1] = v.y; t[r][c4+2] = v.z; t[r][c4+3] = v.w;
    }
    __syncthreads();
    {
        const int n = tid >> 3, kc = (tid & 7) * 4;
        half4v h;
        h.x = (_Float16)t[kc+0][n];
        h.y = (_Float16)t[kc+1][n];
        h.z = (_Float16)t[kc+2][n];
        h.w = (_Float16)t[kc+3][n];
        *(half4v*)&dst[(size_t)(n0 + n) * 1024 + k0 + kc] = h;
    }
}

// ---------------------------------------------------------------------------
// fp16 GEMM, PIPELINED: 128x128 tile, BK=32, FOUR LDS buffers (64 KB),
// 2-K-tile lookahead. Per K-tile: STAGE(t+2) -> counted vmcnt(8) (FIFO:
// guarantees tile t landed, t+1/t+2 stay in flight) -> raw s_barrier +
// sched_barrier(0) -> ds_read frags + 16 MFMA. ONE barrier per K-tile,
// never vmcnt(0) mid-loop. Fragment addressing identical to the proven
// m97 kernel. EPI 0: qkv epilogue; EPI 1: proj (fp32 out).
// ---------------------------------------------------------------------------
template<int EPI>
__global__ __launch_bounds__(256) void gemm_s_kernel(
    const _Float16* __restrict__ A,
    const _Float16* __restrict__ Bt, const float* __restrict__ bias,
    _Float16* __restrict__ oq, _Float16* __restrict__ ok,
    _Float16* __restrict__ ovt, float* __restrict__ oproj)
{
    __shared__ alignas(16) _Float16 As[4][128*32];   // 8 KB per buf
    __shared__ alignas(16) _Float16 Bs[4][128*32];
    const int tid = threadIdx.x;
    const int lane = tid & 63, w = tid >> 6;
    const int wm = w >> 1, wn = w & 1;
    const int m0 = blockIdx.y * 128, n0 = blockIdx.x * 128;

    f32x4 acc[4][4];
    #pragma unroll
    for (int i = 0; i < 4; ++i)
        #pragma unroll
        for (int j = 0; j < 4; ++j) acc[i][j] = (f32x4){0.f, 0.f, 0.f, 0.f};

    int srow[2], scol[2];
    #pragma unroll
    for (int e = 0; e < 2; ++e) {
        const int L = (tid + e * 256) * 16;
        srow[e] = L >> 6;
        scol[e] = (L & 63) ^ ((srow[e] & 3) << 4);
    }
    const int dbase0 = w * 1024;
    const int dbase1 = w * 1024 + 4096;

    // 4 gl16 per STAGEKT per thread (A e0/e1, B e0/e1) -> vmcnt counts 4/tile
    #define STAGEKT(t)                                                             \
        {                                                                          \
            const int _b = (t) & 3;                                                \
            const size_t _k2 = (size_t)(t) * 64;                                   \
            gl16((const char*)A  + (size_t)(m0 + srow[0]) * 2048 + _k2 + scol[0],  \
                 (char*)&As[_b][0] + dbase0);                                      \
            gl16((const char*)A  + (size_t)(m0 + srow[1]) * 2048 + _k2 + scol[1],  \
                 (char*)&As[_b][0] + dbase1);                                      \
            gl16((const char*)Bt + (size_t)(n0 + srow[0]) * 2048 + _k2 + scol[0],  \
                 (char*)&Bs[_b][0] + dbase0);                                      \
            gl16((const char*)Bt + (size_t)(n0 + srow[1]) * 2048 + _k2 + scol[1],  \
                 (char*)&Bs[_b][0] + dbase1);                                      \
        }

    STAGEKT(0);
    STAGEKT(1);

    #pragma unroll 1
    for (int t = 0; t < 32; ++t) {
        if (t + 2 < 32) {
            STAGEKT(t + 2);
            asm volatile("s_waitcnt vmcnt(8)" ::: "memory");
        } else if (t + 1 < 32) {
            asm volatile("s_waitcnt vmcnt(4)" ::: "memory");
        } else {
            asm volatile("s_waitcnt vmcnt(0)" ::: "memory");
        }
        __builtin_amdgcn_s_barrier();
        __builtin_amdgcn_sched_barrier(0);

        const char* Ab = (const char*)&As[t & 3][0];
        const char* Bb = (const char*)&Bs[t & 3][0];
        half8 ah[4], bb[4];
        const int kb = (lane >> 4) * 16;
        #pragma unroll
        for (int f = 0; f < 4; ++f) {
            const int ra = wm * 64 + f * 16 + (lane & 15);
            ah[f] = *(const half8*)(Ab + ra * 64 + (kb ^ ((ra & 3) << 4)));
            const int rb = wn * 64 + f * 16 + (lane & 15);
            bb[f] = *(const half8*)(Bb + rb * 64 + (kb ^ ((rb & 3) << 4)));
        }
        __builtin_amdgcn_s_setprio(1);
        #pragma unroll
        for (int i = 0; i < 4; ++i)
            #pragma unroll
            for (int j = 0; j < 4; ++j)
                acc[i][j] = MFMAH(ah[i], bb[j], acc[i][j]);
        __builtin_amdgcn_s_setprio(0);
    }
    #undef STAGEKT

    const int cg = lane & 15, rg = lane >> 4;
    #pragma unroll
    for (int j = 0; j < 4; ++j) {
        const int col = n0 + wn * 64 + j * 16 + cg;
        const float bv = bias[col];
        #pragma unroll
        for (int i = 0; i < 4; ++i) {
            #pragma unroll
            for (int r = 0; r < 4; ++r) {
                const int row = m0 + wm * 64 + i * 16 + rg * 4 + r;
                const float val = acc[i][j][r] + bv;
                if (EPI == 0) {
                    const int which = col >> 10;
                    const int cc = col & 1023;
                    const int h = cc >> 6, d = cc & 63;
                    const int b = row >> 11, n = row & 2047;
                    const int bh_ = b * H_ + h;
                    if (which == 0)
                        oq[((size_t)bh_ * N_ + n) * D_ + d] = (_Float16)(val * QSCALE);
                    else if (which == 1)
                        ok[((size_t)bh_ * N_ + n) * D_ + d] = (_Float16)val;
                    else
                        ovt[((size_t)bh_ * D_ + d) * N_ + n] = (_Float16)val;
                } else {
                    oproj[(size_t)row * C_ + col] = val;
                }
            }
        }
    }
}

// ---------------------------------------------------------------------------
// MFMA flash attention (r21 version, unchanged): XCD-swizzled 1D grid
// (bh = (id&7)*4 + (id>>3)&3 -> per-XCD K/V L2-resident), KV tile 64,
// K+V dbuf LDS 32KB, swapped QK^T, no online max (log2-domain scores),
// in-lane VALU row sum, P in regs via pk2+permlane32_swap.
// ---------------------------------------------------------------------------
__global__ __launch_bounds__(256, 2) void attn_mfma_kernel(
    const _Float16* __restrict__ q,   // [32][2048][64]
    const _Float16* __restrict__ k,   // [32][2048][64]
    const _Float16* __restrict__ vt,  // [32][64][2048]
    _Float16* __restrict__ ao)        // [4096][1024]
{
    __shared__ alignas(16) _Float16 Ks[2][4096];
    __shared__ alignas(16) _Float16 Vs[2][4096];
    const int tid = threadIdx.x, lane = tid & 63, w = tid >> 6;
    const int id = blockIdx.x;
    const int bh = (id & 7) * 4 + ((id >> 3) & 3);   // XCD (id&7) owns 4 heads
    const int q0 = (id >> 5) * 128;
    const _Float16* qp = q + (size_t)bh * N_ * D_;
    const _Float16* kp = k + (size_t)bh * N_ * D_;
    const _Float16* vp = vt + (size_t)bh * D_ * N_;

    const int lq = lane & 31, lh = lane >> 5;

    half8 qb[4];
    {
        const int qr = q0 + w * 32 + lq;
        #pragma unroll
        for (int ds = 0; ds < 4; ++ds)
            qb[ds] = *(const half8*)(qp + (size_t)qr * D_ + ds * 16 + lh * 8);
    }

    const int c0 = w * 2, c1 = w * 2 + 1;
    const int rr0 = ((c0 & 1) << 5) + (lane >> 1), ss0 = c0 >> 1;
    const int rr1 = ((c1 & 1) << 5) + (lane >> 1), ss1 = c1 >> 1;
    const int hh = lane & 1;

    f32x16 o0, o1;
    #pragma unroll
    for (int r = 0; r < 16; ++r) { o0[r] = 0.f; o1[r] = 0.f; }
    float sum0 = 0.f, sum1 = 0.f, sum2 = 0.f, sum3 = 0.f;

    gl16(kp + (size_t)(rr0) * 64 + ss0 * 16 + hh * 8, (char*)&Ks[0][0] + c0 * 1024);
    gl16(kp + (size_t)(rr1) * 64 + ss1 * 16 + hh * 8, (char*)&Ks[0][0] + c1 * 1024);
    gl16(vp + (size_t)rr0 * 2048 + ss0 * 16 + hh * 8, (char*)&Vs[0][0] + c0 * 1024);
    gl16(vp + (size_t)rr1 * 2048 + ss1 * 16 + hh * 8, (char*)&Vs[0][0] + c1 * 1024);
    __syncthreads();

    int cur = 0;
    for (int t = 0; t < N_ / 64; ++t) {
        if (t + 1 < N_ / 64) {
            const int t0 = (t + 1) << 6;
            const int nb = cur ^ 1;
            gl16(kp + (size_t)(t0 + rr0) * 64 + ss0 * 16 + hh * 8, (char*)&Ks[nb][0] + c0 * 1024);
            gl16(kp + (size_t)(t0 + rr1) * 64 + ss1 * 16 + hh * 8, (char*)&Ks[nb][0] + c1 * 1024);
            gl16(vp + (size_t)rr0 * 2048 + t0 + ss0 * 16 + hh * 8, (char*)&Vs[nb][0] + c0 * 1024);
            gl16(vp + (size_t)rr1 * 2048 + t0 + ss1 * 16 + hh * 8, (char*)&Vs[nb][0] + c1 * 1024);
        }

        // ---- QK^T (swapped): S^T[key][q], lane col = q ----
        f32x16 s0, s1;
        #pragma unroll
        for (int r = 0; r < 16; ++r) { s0[r] = 0.f; s1[r] = 0.f; }
        __builtin_amdgcn_s_setprio(1);
        #pragma unroll
        for (int ds = 0; ds < 4; ++ds) {
            const half8 kf0 = *(const half8*)((const char*)&Ks[cur][0]
                              + ds * 2048 + lq * 32 + lh * 16);
            const half8 kf1 = *(const half8*)((const char*)&Ks[cur][0]
                              + ds * 2048 + (32 + lq) * 32 + lh * 16);
            s0 = MFMA32(kf0, qb[ds], s0);
            s1 = MFMA32(kf1, qb[ds], s1);
        }
        __builtin_amdgcn_s_setprio(0);

        // ---- P = exp2(S) + in-lane row-sum accumulation ----
        float pv[2][16];
        #pragma unroll
        for (int r = 0; r < 16; r += 4) {
            pv[0][r+0] = __builtin_amdgcn_exp2f(s0[r+0]);
            pv[0][r+1] = __builtin_amdgcn_exp2f(s0[r+1]);
            pv[0][r+2] = __builtin_amdgcn_exp2f(s0[r+2]);
            pv[0][r+3] = __builtin_amdgcn_exp2f(s0[r+3]);
            pv[1][r+0] = __builtin_amdgcn_exp2f(s1[r+0]);
            pv[1][r+1] = __builtin_amdgcn_exp2f(s1[r+1]);
            pv[1][r+2] = __builtin_amdgcn_exp2f(s1[r+2]);
            pv[1][r+3] = __builtin_amdgcn_exp2f(s1[r+3]);
            sum0 += pv[0][r+0] + pv[1][r+0];
            sum1 += pv[0][r+1] + pv[1][r+1];
            sum2 += pv[0][r+2] + pv[1][r+2];
            sum3 += pv[0][r+3] + pv[1][r+3];
        }

        // ---- assemble PV A-frags in registers via permlane32_swap ----
        half8 pa[4];
        #pragma unroll
        for (int sl = 0; sl < 4; ++sl) {
            const int blk = sl >> 1, rb = (sl & 1) * 8;
            unsigned A0 = pk2(pv[blk][rb + 0], pv[blk][rb + 1]);
            unsigned A1 = pk2(pv[blk][rb + 2], pv[blk][rb + 3]);
            unsigned B0 = pk2(pv[blk][rb + 4], pv[blk][rb + 5]);
            unsigned B1 = pk2(pv[blk][rb + 6], pv[blk][rb + 7]);
            asm volatile("v_permlane32_swap_b32 %0, %1" : "+v"(A0), "+v"(B0));
            asm volatile("v_permlane32_swap_b32 %0, %1" : "+v"(A1), "+v"(B1));
            union { unsigned u[4]; half8 h; } uu;
            uu.u[0] = A0; uu.u[1] = A1; uu.u[2] = B0; uu.u[3] = B1;
            pa[sl] = uu.h;
        }

        // ---- PV ----
        __builtin_amdgcn_s_setprio(1);
        #pragma unroll
        for (int sl = 0; sl < 4; ++sl) {
            const half8 v0 = *(const half8*)((const char*)&Vs[cur][0]
                             + sl * 2048 + lq * 32 + lh * 16);
            const half8 v1 = *(const half8*)((const char*)&Vs[cur][0]
                             + sl * 2048 + (32 + lq) * 32 + lh * 16);
            o0 = MFMA32(pa[sl], v0, o0);
            o1 = MFMA32(pa[sl], v1, o1);
        }
        __builtin_amdgcn_s_setprio(0);

        __syncthreads();
        cur ^= 1;
    }

    // ---- cross-half combine of the row sum (lane (lq,0) <-> (lq,1)) ----
    const float partial = (sum0 + sum1) + (sum2 + sum3);
    {
        unsigned X = __builtin_bit_cast(unsigned, partial);
        unsigned Y = __builtin_bit_cast(unsigned, partial);
        asm volatile("v_permlane32_swap_b32 %0, %1" : "+v"(X), "+v"(Y));
        const float other = lh ? __builtin_bit_cast(float, X)
                               : __builtin_bit_cast(float, Y);
        const float full = partial + other;
        const float inv = 1.0f / full;

        const int b = bh >> 4, h = bh & 15;
        #pragma unroll
        for (int r = 0; r < 16; ++r) {
            const int rowq = (r & 3) + 8 * (r >> 2) + 4 * lh;
            const float li = __shfl(inv, rowq, 64);
            const int n = q0 + w * 32 + rowq;
            _Float16* dst = ao + ((size_t)(b * N_ + n)) * C_ + h * D_;
            dst[lq]      = (_Float16)(o0[r] * li);
            dst[32 + lq] = (_Float16)(o1[r] * li);
        }
    }
}

// ---------------------------------------------------------------------------
extern "C" void kernel_launch(void* const* d_in, const int* in_sizes, int n_in,
                              void* d_out, int out_size, void* d_ws, size_t ws_size,
                              hipStream_t stream) {
    const float* x      = (const float*)d_in[0];
    const float* w_qkv  = (const float*)d_in[1];
    const float* b_qkv  = (const float*)d_in[2];
    const float* w_proj = (const float*)d_in[3];
    const float* b_proj = (const float*)d_in[4];
    float* out = (float*)d_out;

    char* wsb = (char*)d_ws;
    const size_t MB = 1u << 20;
    _Float16* xh  = (_Float16*)(wsb + 0);        // 8 MB [4096][1024]
    _Float16* wqT = (_Float16*)(wsb + 8*MB);     // 6 MB [3072][1024]
    _Float16* wpT = (_Float16*)(wsb + 14*MB);    // 2 MB [1024][1024]
    _Float16* qb  = (_Float16*)(wsb + 16*MB);    // 8 MB [32][2048][64]
    _Float16* kb  = (_Float16*)(wsb + 24*MB);    // 8 MB
    _Float16* vtb = (_Float16*)(wsb + 32*MB);    // 8 MB [32][64][2048]
    _Float16* ao  = (_Float16*)(wsb + 0);        // alias xh (dead after QKV gemm)

    prep_kernel<<<6144, 256, 0, stream>>>(x, w_qkv, w_proj, xh, wqT, wpT);

    gemm_s_kernel<0><<<dim3(QKV_N/128, M_TOT/128), 256, 0, stream>>>(
        xh, wqT, b_qkv, qb, kb, vtb, nullptr);

    attn_mfma_kernel<<<512, 256, 0, stream>>>(qb, kb, vtb, ao);

    gemm_s_kernel<1><<<dim3(C_/128, M_TOT/128), 256, 0, stream>>>(
        ao, wpT, b_proj, nullptr, nullptr, nullptr, out);
}

// Round 24
// 134.841 us; speedup vs baseline: 1.0030x; 1.0030x over previous
//
#include <hip/hip_runtime.h>
#include <cstdint>

#define B_ 2
#define N_ 2048
#define C_ 1024
#define H_ 16
#define D_ 64
#define M_TOT 4096
#define QKV_N 3072
#define BH_ 32
static constexpr float SCALE = 0.125f;            // 64^-0.5
static constexpr float LOG2E = 1.44269504088896f;
static constexpr float QSCALE = SCALE * LOG2E;    // baked into stored q

typedef __attribute__((ext_vector_type(8))) _Float16 half8;   // 4 VGPR
typedef __attribute__((ext_vector_type(4))) _Float16 half4v;
typedef __attribute__((ext_vector_type(2))) __fp16 fp16x2;
typedef __attribute__((ext_vector_type(4))) float f32x4;
typedef __attribute__((ext_vector_type(16))) float f32x16;

#define MFMAH(a, b, c)  __builtin_amdgcn_mfma_f32_16x16x32_f16((a), (b), (c), 0, 0, 0)
#define MFMA32(a, b, c) __builtin_amdgcn_mfma_f32_32x32x16_f16((a), (b), (c), 0, 0, 0)

__device__ inline void gl16(const void* g, void* l) {
    __builtin_amdgcn_global_load_lds(
        (const __attribute__((address_space(1))) unsigned int*)g,
        (__attribute__((address_space(3))) unsigned int*)l, 16, 0, 0);
}

__device__ inline unsigned pk2(float a, float b) {
    fp16x2 t = __builtin_amdgcn_cvt_pkrtz(a, b);
    return __builtin_bit_cast(unsigned, t);
}

// ---------------------------------------------------------------------------
// Merged pre-pass (one launch)
// ---------------------------------------------------------------------------
__global__ __launch_bounds__(256) void prep_kernel(
    const float* __restrict__ x, const float* __restrict__ w_qkv,
    const float* __restrict__ w_proj,
    _Float16* __restrict__ xh, _Float16* __restrict__ wqT,
    _Float16* __restrict__ wpT)
{
    const int bid = blockIdx.x, tid = threadIdx.x;
    if (bid < 2048) {
        #pragma unroll
        for (int e = 0; e < 2; ++e) {
            const int i = bid * 256 + tid + e * 524288;
            const float4 v = ((const float4*)x)[i];
            half4v h;
            h.x = (_Float16)v.x; h.y = (_Float16)v.y;
            h.z = (_Float16)v.z; h.w = (_Float16)v.w;
            ((half4v*)xh)[i] = h;
        }
        return;
    }
    __shared__ float t[32][33];
    const float* src;
    _Float16* dst;
    int Ncols, n0, k0;
    if (bid < 5120) {
        const int b = bid - 2048;
        src = w_qkv; dst = wqT; Ncols = QKV_N;
        n0 = (b % 96) * 32; k0 = (b / 96) * 32;
    } else {
        const int b = bid - 5120;
        src = w_proj; dst = wpT; Ncols = C_;
        n0 = (b & 31) * 32; k0 = (b >> 5) * 32;
    }
    {
        const int r = tid >> 3, c4 = (tid & 7) * 4;
        const float4 v = *(const float4*)&src[(size_t)(k0 + r) * Ncols + n0 + c4];
        t[r][c4+0] = v.x; t[r][c4+1] = v.y; t[r][c4+2] = v.z; t[r][c4+3] = v.w;
    }
    __syncthreads();
    {
        const int n = tid >> 3, kc = (tid & 7) * 4;
        half4v h;
        h.x = (_Float16)t[kc+0][n];
        h.y = (_Float16)t[kc+1][n];
        h.z = (_Float16)t[kc+2][n];
        h.w = (_Float16)t[kc+3][n];
        *(half4v*)&dst[(size_t)(n0 + n) * 1024 + k0 + kc] = h;
    }
}

// ---------------------------------------------------------------------------
// fp16 GEMM, m97 structure + per-XCD B-panel swizzle: 128x128 tile, BK=32,
// single-buffered 16KB LDS, gl16 staging, 4-5 blocks/CU. 1D grid with
// CPX = NBX/8 B-columns per XCD: col=(id%8)*CPX+(id/8)%CPX, row=id/(8*CPX)
// (bijective; XCD id%8 keeps its B panel L2-resident, as proven on attn).
// EPI 0: qkv epilogue; EPI 1: proj (fp32 out).
// ---------------------------------------------------------------------------
template<int EPI, int NBX>
__global__ __launch_bounds__(256) void gemm_s_kernel(
    const _Float16* __restrict__ A,
    const _Float16* __restrict__ Bt, const float* __restrict__ bias,
    _Float16* __restrict__ oq, _Float16* __restrict__ ok,
    _Float16* __restrict__ ovt, float* __restrict__ oproj)
{
    __shared__ alignas(16) _Float16 As[128*32];   // 8 KB, rows = 64 B
    __shared__ alignas(16) _Float16 Bs[128*32];
    const int tid = threadIdx.x;
    const int lane = tid & 63, w = tid >> 6;
    const int wm = w >> 1, wn = w & 1;

    constexpr int CPX = NBX / 8;
    const int id = blockIdx.x;
    const int col = (id % 8) * CPX + (id / 8) % CPX;
    const int row = id / (8 * CPX);
    const int n0 = col * 128, m0 = row * 128;

    f32x4 acc[4][4];
    #pragma unroll
    for (int i = 0; i < 4; ++i)
        #pragma unroll
        for (int j = 0; j < 4; ++j) acc[i][j] = (f32x4){0.f, 0.f, 0.f, 0.f};

    int srow[2], scol[2];
    #pragma unroll
    for (int e = 0; e < 2; ++e) {
        const int L = (tid + e * 256) * 16;
        srow[e] = L >> 6;
        scol[e] = (L & 63) ^ ((srow[e] & 3) << 4);
    }
    const int dbase0 = w * 1024;
    const int dbase1 = w * 1024 + 4096;

    for (int t = 0; t < 32; ++t) {
        const int k0 = t * 32;
        gl16((const char*)A  + (size_t)(m0 + srow[0]) * 2048 + k0 * 2 + scol[0],
             (char*)As + dbase0);
        gl16((const char*)A  + (size_t)(m0 + srow[1]) * 2048 + k0 * 2 + scol[1],
             (char*)As + dbase1);
        gl16((const char*)Bt + (size_t)(n0 + srow[0]) * 2048 + k0 * 2 + scol[0],
             (char*)Bs + dbase0);
        gl16((const char*)Bt + (size_t)(n0 + srow[1]) * 2048 + k0 * 2 + scol[1],
             (char*)Bs + dbase1);
        __syncthreads();

        half8 ah[4], bb[4];
        const int kb = (lane >> 4) * 16;
        #pragma unroll
        for (int f = 0; f < 4; ++f) {
            const int ra = wm * 64 + f * 16 + (lane & 15);
            ah[f] = *(const half8*)((const char*)As + ra * 64 + (kb ^ ((ra & 3) << 4)));
            const int rb = wn * 64 + f * 16 + (lane & 15);
            bb[f] = *(const half8*)((const char*)Bs + rb * 64 + (kb ^ ((rb & 3) << 4)));
        }
        #pragma unroll
        for (int i = 0; i < 4; ++i)
            #pragma unroll
            for (int j = 0; j < 4; ++j)
                acc[i][j] = MFMAH(ah[i], bb[j], acc[i][j]);
        __syncthreads();
    }

    const int cg = lane & 15, rg = lane >> 4;
    #pragma unroll
    for (int j = 0; j < 4; ++j) {
        const int ccol = n0 + wn * 64 + j * 16 + cg;
        const float bv = bias[ccol];
        #pragma unroll
        for (int i = 0; i < 4; ++i) {
            #pragma unroll
            for (int r = 0; r < 4; ++r) {
                const int rrow = m0 + wm * 64 + i * 16 + rg * 4 + r;
                const float val = acc[i][j][r] + bv;
                if (EPI == 0) {
                    const int which = ccol >> 10;
                    const int cc = ccol & 1023;
                    const int h = cc >> 6, d = cc & 63;
                    const int b = rrow >> 11, n = rrow & 2047;
                    const int bh_ = b * H_ + h;
                    if (which == 0)
                        oq[((size_t)bh_ * N_ + n) * D_ + d] = (_Float16)(val * QSCALE);
                    else if (which == 1)
                        ok[((size_t)bh_ * N_ + n) * D_ + d] = (_Float16)val;
                    else
                        ovt[((size_t)bh_ * D_ + d) * N_ + n] = (_Float16)val;
                } else {
                    oproj[(size_t)rrow * C_ + ccol] = val;
                }
            }
        }
    }
}

// ---------------------------------------------------------------------------
// MFMA flash attention (r21 version, unchanged): XCD-swizzled 1D grid
// (bh = (id&7)*4 + (id>>3)&3 -> per-XCD K/V L2-resident), KV tile 64,
// K+V dbuf LDS 32KB, swapped QK^T, no online max (log2-domain scores),
// in-lane VALU row sum, P in regs via pk2+permlane32_swap.
// ---------------------------------------------------------------------------
__global__ __launch_bounds__(256, 2) void attn_mfma_kernel(
    const _Float16* __restrict__ q,   // [32][2048][64]
    const _Float16* __restrict__ k,   // [32][2048][64]
    const _Float16* __restrict__ vt,  // [32][64][2048]
    _Float16* __restrict__ ao)        // [4096][1024]
{
    __shared__ alignas(16) _Float16 Ks[2][4096];
    __shared__ alignas(16) _Float16 Vs[2][4096];
    const int tid = threadIdx.x, lane = tid & 63, w = tid >> 6;
    const int id = blockIdx.x;
    const int bh = (id & 7) * 4 + ((id >> 3) & 3);   // XCD (id&7) owns 4 heads
    const int q0 = (id >> 5) * 128;
    const _Float16* qp = q + (size_t)bh * N_ * D_;
    const _Float16* kp = k + (size_t)bh * N_ * D_;
    const _Float16* vp = vt + (size_t)bh * D_ * N_;

    const int lq = lane & 31, lh = lane >> 5;

    half8 qb[4];
    {
        const int qr = q0 + w * 32 + lq;
        #pragma unroll
        for (int ds = 0; ds < 4; ++ds)
            qb[ds] = *(const half8*)(qp + (size_t)qr * D_ + ds * 16 + lh * 8);
    }

    const int c0 = w * 2, c1 = w * 2 + 1;
    const int rr0 = ((c0 & 1) << 5) + (lane >> 1), ss0 = c0 >> 1;
    const int rr1 = ((c1 & 1) << 5) + (lane >> 1), ss1 = c1 >> 1;
    const int hh = lane & 1;

    f32x16 o0, o1;
    #pragma unroll
    for (int r = 0; r < 16; ++r) { o0[r] = 0.f; o1[r] = 0.f; }
    float sum0 = 0.f, sum1 = 0.f, sum2 = 0.f, sum3 = 0.f;

    gl16(kp + (size_t)(rr0) * 64 + ss0 * 16 + hh * 8, (char*)&Ks[0][0] + c0 * 1024);
    gl16(kp + (size_t)(rr1) * 64 + ss1 * 16 + hh * 8, (char*)&Ks[0][0] + c1 * 1024);
    gl16(vp + (size_t)rr0 * 2048 + ss0 * 16 + hh * 8, (char*)&Vs[0][0] + c0 * 1024);
    gl16(vp + (size_t)rr1 * 2048 + ss1 * 16 + hh * 8, (char*)&Vs[0][0] + c1 * 1024);
    __syncthreads();

    int cur = 0;
    for (int t = 0; t < N_ / 64; ++t) {
        if (t + 1 < N_ / 64) {
            const int t0 = (t + 1) << 6;
            const int nb = cur ^ 1;
            gl16(kp + (size_t)(t0 + rr0) * 64 + ss0 * 16 + hh * 8, (char*)&Ks[nb][0] + c0 * 1024);
            gl16(kp + (size_t)(t0 + rr1) * 64 + ss1 * 16 + hh * 8, (char*)&Ks[nb][0] + c1 * 1024);
            gl16(vp + (size_t)rr0 * 2048 + t0 + ss0 * 16 + hh * 8, (char*)&Vs[nb][0] + c0 * 1024);
            gl16(vp + (size_t)rr1 * 2048 + t0 + ss1 * 16 + hh * 8, (char*)&Vs[nb][0] + c1 * 1024);
        }

        // ---- QK^T (swapped): S^T[key][q], lane col = q ----
        f32x16 s0, s1;
        #pragma unroll
        for (int r = 0; r < 16; ++r) { s0[r] = 0.f; s1[r] = 0.f; }
        __builtin_amdgcn_s_setprio(1);
        #pragma unroll
        for (int ds = 0; ds < 4; ++ds) {
            const half8 kf0 = *(const half8*)((const char*)&Ks[cur][0]
                              + ds * 2048 + lq * 32 + lh * 16);
            const half8 kf1 = *(const half8*)((const char*)&Ks[cur][0]
                              + ds * 2048 + (32 + lq) * 32 + lh * 16);
            s0 = MFMA32(kf0, qb[ds], s0);
            s1 = MFMA32(kf1, qb[ds], s1);
        }
        __builtin_amdgcn_s_setprio(0);

        // ---- P = exp2(S) + in-lane row-sum accumulation ----
        float pv[2][16];
        #pragma unroll
        for (int r = 0; r < 16; r += 4) {
            pv[0][r+0] = __builtin_amdgcn_exp2f(s0[r+0]);
            pv[0][r+1] = __builtin_amdgcn_exp2f(s0[r+1]);
            pv[0][r+2] = __builtin_amdgcn_exp2f(s0[r+2]);
            pv[0][r+3] = __builtin_amdgcn_exp2f(s0[r+3]);
            pv[1][r+0] = __builtin_amdgcn_exp2f(s1[r+0]);
            pv[1][r+1] = __builtin_amdgcn_exp2f(s1[r+1]);
            pv[1][r+2] = __builtin_amdgcn_exp2f(s1[r+2]);
            pv[1][r+3] = __builtin_amdgcn_exp2f(s1[r+3]);
            sum0 += pv[0][r+0] + pv[1][r+0];
            sum1 += pv[0][r+1] + pv[1][r+1];
            sum2 += pv[0][r+2] + pv[1][r+2];
            sum3 += pv[0][r+3] + pv[1][r+3];
        }

        // ---- assemble PV A-frags in registers via permlane32_swap ----
        half8 pa[4];
        #pragma unroll
        for (int sl = 0; sl < 4; ++sl) {
            const int blk = sl >> 1, rb = (sl & 1) * 8;
            unsigned A0 = pk2(pv[blk][rb + 0], pv[blk][rb + 1]);
            unsigned A1 = pk2(pv[blk][rb + 2], pv[blk][rb + 3]);
            unsigned B0 = pk2(pv[blk][rb + 4], pv[blk][rb + 5]);
            unsigned B1 = pk2(pv[blk][rb + 6], pv[blk][rb + 7]);
            asm volatile("v_permlane32_swap_b32 %0, %1" : "+v"(A0), "+v"(B0));
            asm volatile("v_permlane32_swap_b32 %0, %1" : "+v"(A1), "+v"(B1));
            union { unsigned u[4]; half8 h; } uu;
            uu.u[0] = A0; uu.u[1] = A1; uu.u[2] = B0; uu.u[3] = B1;
            pa[sl] = uu.h;
        }

        // ---- PV ----
        __builtin_amdgcn_s_setprio(1);
        #pragma unroll
        for (int sl = 0; sl < 4; ++sl) {
            const half8 v0 = *(const half8*)((const char*)&Vs[cur][0]
                             + sl * 2048 + lq * 32 + lh * 16);
            const half8 v1 = *(const half8*)((const char*)&Vs[cur][0]
                             + sl * 2048 + (32 + lq) * 32 + lh * 16);
            o0 = MFMA32(pa[sl], v0, o0);
            o1 = MFMA32(pa[sl], v1, o1);
        }
        __builtin_amdgcn_s_setprio(0);

        __syncthreads();
        cur ^= 1;
    }

    // ---- cross-half combine of the row sum (lane (lq,0) <-> (lq,1)) ----
    const float partial = (sum0 + sum1) + (sum2 + sum3);
    {
        unsigned X = __builtin_bit_cast(unsigned, partial);
        unsigned Y = __builtin_bit_cast(unsigned, partial);
        asm volatile("v_permlane32_swap_b32 %0, %1" : "+v"(X), "+v"(Y));
        const float other = lh ? __builtin_bit_cast(float, X)
                               : __builtin_bit_cast(float, Y);
        const float full = partial + other;
        const float inv = 1.0f / full;

        const int b = bh >> 4, h = bh & 15;
        #pragma unroll
        for (int r = 0; r < 16; ++r) {
            const int rowq = (r & 3) + 8 * (r >> 2) + 4 * lh;
            const float li = __shfl(inv, rowq, 64);
            const int n = q0 + w * 32 + rowq;
            _Float16* dst = ao + ((size_t)(b * N_ + n)) * C_ + h * D_;
            dst[lq]      = (_Float16)(o0[r] * li);
            dst[32 + lq] = (_Float16)(o1[r] * li);
        }
    }
}

// ---------------------------------------------------------------------------
extern "C" void kernel_launch(void* const* d_in, const int* in_sizes, int n_in,
                              void* d_out, int out_size, void* d_ws, size_t ws_size,
                              hipStream_t stream) {
    const float* x      = (const float*)d_in[0];
    const float* w_qkv  = (const float*)d_in[1];
    const float* b_qkv  = (const float*)d_in[2];
    const float* w_proj = (const float*)d_in[3];
    const float* b_proj = (const float*)d_in[4];
    float* out = (float*)d_out;

    char* wsb = (char*)d_ws;
    const size_t MB = 1u << 20;
    _Float16* xh  = (_Float16*)(wsb + 0);        // 8 MB [4096][1024]
    _Float16* wqT = (_Float16*)(wsb + 8*MB);     // 6 MB [3072][1024]
    _Float16* wpT = (_Float16*)(wsb + 14*MB);    // 2 MB [1024][1024]
    _Float16* qb  = (_Float16*)(wsb + 16*MB);    // 8 MB [32][2048][64]
    _Float16* kb  = (_Float16*)(wsb + 24*MB);    // 8 MB
    _Float16* vtb = (_Float16*)(wsb + 32*MB);    // 8 MB [32][64][2048]
    _Float16* ao  = (_Float16*)(wsb + 0);        // alias xh (dead after QKV gemm)

    prep_kernel<<<6144, 256, 0, stream>>>(x, w_qkv, w_proj, xh, wqT, wpT);

    gemm_s_kernel<0, 24><<<768, 256, 0, stream>>>(
        xh, wqT, b_qkv, qb, kb, vtb, nullptr);

    attn_mfma_kernel<<<512, 256, 0, stream>>>(qb, kb, vtb, ao);

    gemm_s_kernel<1, 8><<<256, 256, 0, stream>>>(
        ao, wpT, b_proj, nullptr, nullptr, nullptr, out);
}

// Round 25
// 124.177 us; speedup vs baseline: 1.0892x; 1.0859x over previous
//
#include <hip/hip_runtime.h>
#include <cstdint>

#define B_ 2
#define N_ 2048
#define C_ 1024
#define H_ 16
#define D_ 64
#define M_TOT 4096
#define QKV_N 3072
#define BH_ 32
static constexpr float SCALE = 0.125f;            // 64^-0.5
static constexpr float LOG2E = 1.44269504088896f;
static constexpr float QSCALE = SCALE * LOG2E;    // baked into stored q

typedef __attribute__((ext_vector_type(8))) _Float16 half8;   // 4 VGPR
typedef __attribute__((ext_vector_type(4))) _Float16 half4v;
typedef __attribute__((ext_vector_type(2))) __fp16 fp16x2;
typedef __attribute__((ext_vector_type(4))) float f32x4;
typedef __attribute__((ext_vector_type(16))) float f32x16;

#define MFMAH(a, b, c)  __builtin_amdgcn_mfma_f32_16x16x32_f16((a), (b), (c), 0, 0, 0)
#define MFMA32(a, b, c) __builtin_amdgcn_mfma_f32_32x32x16_f16((a), (b), (c), 0, 0, 0)

__device__ inline void gl16(const void* g, void* l) {
    __builtin_amdgcn_global_load_lds(
        (const __attribute__((address_space(1))) unsigned int*)g,
        (__attribute__((address_space(3))) unsigned int*)l, 16, 0, 0);
}

__device__ inline unsigned pk2(float a, float b) {
    fp16x2 t = __builtin_amdgcn_cvt_pkrtz(a, b);
    return __builtin_bit_cast(unsigned, t);
}

// ---------------------------------------------------------------------------
// Merged pre-pass (one launch)
// ---------------------------------------------------------------------------
__global__ __launch_bounds__(256) void prep_kernel(
    const float* __restrict__ x, const float* __restrict__ w_qkv,
    const float* __restrict__ w_proj,
    _Float16* __restrict__ xh, _Float16* __restrict__ wqT,
    _Float16* __restrict__ wpT)
{
    const int bid = blockIdx.x, tid = threadIdx.x;
    if (bid < 2048) {
        #pragma unroll
        for (int e = 0; e < 2; ++e) {
            const int i = bid * 256 + tid + e * 524288;
            const float4 v = ((const float4*)x)[i];
            half4v h;
            h.x = (_Float16)v.x; h.y = (_Float16)v.y;
            h.z = (_Float16)v.z; h.w = (_Float16)v.w;
            ((half4v*)xh)[i] = h;
        }
        return;
    }
    __shared__ float t[32][33];
    const float* src;
    _Float16* dst;
    int Ncols, n0, k0;
    if (bid < 5120) {
        const int b = bid - 2048;
        src = w_qkv; dst = wqT; Ncols = QKV_N;
        n0 = (b % 96) * 32; k0 = (b / 96) * 32;
    } else {
        const int b = bid - 5120;
        src = w_proj; dst = wpT; Ncols = C_;
        n0 = (b & 31) * 32; k0 = (b >> 5) * 32;
    }
    {
        const int r = tid >> 3, c4 = (tid & 7) * 4;
        const float4 v = *(const float4*)&src[(size_t)(k0 + r) * Ncols + n0 + c4];
        t[r][c4+0] = v.x; t[r][c4+1] = v.y; t[r][c4+2] = v.z; t[r][c4+3] = v.w;
    }
    __syncthreads();
    {
        const int n = tid >> 3, kc = (tid & 7) * 4;
        half4v h;
        h.x = (_Float16)t[kc+0][n];
        h.y = (_Float16)t[kc+1][n];
        h.z = (_Float16)t[kc+2][n];
        h.w = (_Float16)t[kc+3][n];
        *(half4v*)&dst[(size_t)(n0 + n) * 1024 + k0 + kc] = h;
    }
}

// ---------------------------------------------------------------------------
// fp16 GEMM, m97 structure: 128x128 tile, BK=32, single-buffered 16KB LDS,
// gl16 staging, overlap from 4-5 blocks/CU. EPI 0: qkv; EPI 1: proj.
// (2D y-major grid — default dispatch preserves epilogue write locality.)
// ---------------------------------------------------------------------------
template<int EPI>
__global__ __launch_bounds__(256) void gemm_s_kernel(
    const _Float16* __restrict__ A,
    const _Float16* __restrict__ Bt, const float* __restrict__ bias,
    _Float16* __restrict__ oq, _Float16* __restrict__ ok,
    _Float16* __restrict__ ovt, float* __restrict__ oproj)
{
    __shared__ alignas(16) _Float16 As[128*32];   // 8 KB, rows = 64 B
    __shared__ alignas(16) _Float16 Bs[128*32];
    const int tid = threadIdx.x;
    const int lane = tid & 63, w = tid >> 6;
    const int wm = w >> 1, wn = w & 1;
    const int m0 = blockIdx.y * 128, n0 = blockIdx.x * 128;

    f32x4 acc[4][4];
    #pragma unroll
    for (int i = 0; i < 4; ++i)
        #pragma unroll
        for (int j = 0; j < 4; ++j) acc[i][j] = (f32x4){0.f, 0.f, 0.f, 0.f};

    int srow[2], scol[2];
    #pragma unroll
    for (int e = 0; e < 2; ++e) {
        const int L = (tid + e * 256) * 16;
        srow[e] = L >> 6;
        scol[e] = (L & 63) ^ ((srow[e] & 3) << 4);
    }
    const int dbase0 = w * 1024;
    const int dbase1 = w * 1024 + 4096;

    for (int t = 0; t < 32; ++t) {
        const int k0 = t * 32;
        gl16((const char*)A  + (size_t)(m0 + srow[0]) * 2048 + k0 * 2 + scol[0],
             (char*)As + dbase0);
        gl16((const char*)A  + (size_t)(m0 + srow[1]) * 2048 + k0 * 2 + scol[1],
             (char*)As + dbase1);
        gl16((const char*)Bt + (size_t)(n0 + srow[0]) * 2048 + k0 * 2 + scol[0],
             (char*)Bs + dbase0);
        gl16((const char*)Bt + (size_t)(n0 + srow[1]) * 2048 + k0 * 2 + scol[1],
             (char*)Bs + dbase1);
        __syncthreads();

        half8 ah[4], bb[4];
        const int kb = (lane >> 4) * 16;
        #pragma unroll
        for (int f = 0; f < 4; ++f) {
            const int ra = wm * 64 + f * 16 + (lane & 15);
            ah[f] = *(const half8*)((const char*)As + ra * 64 + (kb ^ ((ra & 3) << 4)));
            const int rb = wn * 64 + f * 16 + (lane & 15);
            bb[f] = *(const half8*)((const char*)Bs + rb * 64 + (kb ^ ((rb & 3) << 4)));
        }
        #pragma unroll
        for (int i = 0; i < 4; ++i)
            #pragma unroll
            for (int j = 0; j < 4; ++j)
                acc[i][j] = MFMAH(ah[i], bb[j], acc[i][j]);
        __syncthreads();
    }

    const int cg = lane & 15, rg = lane >> 4;
    #pragma unroll
    for (int j = 0; j < 4; ++j) {
        const int col = n0 + wn * 64 + j * 16 + cg;
        const float bv = bias[col];
        #pragma unroll
        for (int i = 0; i < 4; ++i) {
            #pragma unroll
            for (int r = 0; r < 4; ++r) {
                const int row = m0 + wm * 64 + i * 16 + rg * 4 + r;
                const float val = acc[i][j][r] + bv;
                if (EPI == 0) {
                    const int which = col >> 10;
                    const int cc = col & 1023;
                    const int h = cc >> 6, d = cc & 63;
                    const int b = row >> 11, n = row & 2047;
                    const int bh_ = b * H_ + h;
                    if (which == 0)
                        oq[((size_t)bh_ * N_ + n) * D_ + d] = (_Float16)(val * QSCALE);
                    else if (which == 1)
                        ok[((size_t)bh_ * N_ + n) * D_ + d] = (_Float16)val;
                    else
                        ovt[((size_t)bh_ * D_ + d) * N_ + n] = (_Float16)val;
                } else {
                    oproj[(size_t)row * C_ + col] = val;
                }
            }
        }
    }
}

// ---------------------------------------------------------------------------
// MFMA flash attention: XCD-swizzled 1D grid (bh = (id&7)*4 + (id>>3)&3 ->
// per-XCD K/V L2-resident, FETCH 69.7->12.3 MB measured), KV tile 64,
// K+V dbuf LDS 32KB, swapped QK^T, no online max (log2-domain scores),
// in-lane VALU row sum, P in regs via pk2+permlane32_swap.
// ---------------------------------------------------------------------------
__global__ __launch_bounds__(256, 2) void attn_mfma_kernel(
    const _Float16* __restrict__ q,   // [32][2048][64]
    const _Float16* __restrict__ k,   // [32][2048][64]
    const _Float16* __restrict__ vt,  // [32][64][2048]
    _Float16* __restrict__ ao)        // [4096][1024]
{
    __shared__ alignas(16) _Float16 Ks[2][4096];
    __shared__ alignas(16) _Float16 Vs[2][4096];
    const int tid = threadIdx.x, lane = tid & 63, w = tid >> 6;
    const int id = blockIdx.x;
    const int bh = (id & 7) * 4 + ((id >> 3) & 3);   // XCD (id&7) owns 4 heads
    const int q0 = (id >> 5) * 128;
    const _Float16* qp = q + (size_t)bh * N_ * D_;
    const _Float16* kp = k + (size_t)bh * N_ * D_;
    const _Float16* vp = vt + (size_t)bh * D_ * N_;

    const int lq = lane & 31, lh = lane >> 5;

    half8 qb[4];
    {
        const int qr = q0 + w * 32 + lq;
        #pragma unroll
        for (int ds = 0; ds < 4; ++ds)
            qb[ds] = *(const half8*)(qp + (size_t)qr * D_ + ds * 16 + lh * 8);
    }

    const int c0 = w * 2, c1 = w * 2 + 1;
    const int rr0 = ((c0 & 1) << 5) + (lane >> 1), ss0 = c0 >> 1;
    const int rr1 = ((c1 & 1) << 5) + (lane >> 1), ss1 = c1 >> 1;
    const int hh = lane & 1;

    f32x16 o0, o1;
    #pragma unroll
    for (int r = 0; r < 16; ++r) { o0[r] = 0.f; o1[r] = 0.f; }
    float sum0 = 0.f, sum1 = 0.f, sum2 = 0.f, sum3 = 0.f;

    gl16(kp + (size_t)(rr0) * 64 + ss0 * 16 + hh * 8, (char*)&Ks[0][0] + c0 * 1024);
    gl16(kp + (size_t)(rr1) * 64 + ss1 * 16 + hh * 8, (char*)&Ks[0][0] + c1 * 1024);
    gl16(vp + (size_t)rr0 * 2048 + ss0 * 16 + hh * 8, (char*)&Vs[0][0] + c0 * 1024);
    gl16(vp + (size_t)rr1 * 2048 + ss1 * 16 + hh * 8, (char*)&Vs[0][0] + c1 * 1024);
    __syncthreads();

    int cur = 0;
    for (int t = 0; t < N_ / 64; ++t) {
        if (t + 1 < N_ / 64) {
            const int t0 = (t + 1) << 6;
            const int nb = cur ^ 1;
            gl16(kp + (size_t)(t0 + rr0) * 64 + ss0 * 16 + hh * 8, (char*)&Ks[nb][0] + c0 * 1024);
            gl16(kp + (size_t)(t0 + rr1) * 64 + ss1 * 16 + hh * 8, (char*)&Ks[nb][0] + c1 * 1024);
            gl16(vp + (size_t)rr0 * 2048 + t0 + ss0 * 16 + hh * 8, (char*)&Vs[nb][0] + c0 * 1024);
            gl16(vp + (size_t)rr1 * 2048 + t0 + ss1 * 16 + hh * 8, (char*)&Vs[nb][0] + c1 * 1024);
        }

        // ---- QK^T (swapped): S^T[key][q], lane col = q ----
        f32x16 s0, s1;
        #pragma unroll
        for (int r = 0; r < 16; ++r) { s0[r] = 0.f; s1[r] = 0.f; }
        __builtin_amdgcn_s_setprio(1);
        #pragma unroll
        for (int ds = 0; ds < 4; ++ds) {
            const half8 kf0 = *(const half8*)((const char*)&Ks[cur][0]
                              + ds * 2048 + lq * 32 + lh * 16);
            const half8 kf1 = *(const half8*)((const char*)&Ks[cur][0]
                              + ds * 2048 + (32 + lq) * 32 + lh * 16);
            s0 = MFMA32(kf0, qb[ds], s0);
            s1 = MFMA32(kf1, qb[ds], s1);
        }
        __builtin_amdgcn_s_setprio(0);

        // ---- P = exp2(S) + in-lane row-sum accumulation ----
        float pv[2][16];
        #pragma unroll
        for (int r = 0; r < 16; r += 4) {
            pv[0][r+0] = __builtin_amdgcn_exp2f(s0[r+0]);
            pv[0][r+1] = __builtin_amdgcn_exp2f(s0[r+1]);
            pv[0][r+2] = __builtin_amdgcn_exp2f(s0[r+2]);
            pv[0][r+3] = __builtin_amdgcn_exp2f(s0[r+3]);
            pv[1][r+0] = __builtin_amdgcn_exp2f(s1[r+0]);
            pv[1][r+1] = __builtin_amdgcn_exp2f(s1[r+1]);
            pv[1][r+2] = __builtin_amdgcn_exp2f(s1[r+2]);
            pv[1][r+3] = __builtin_amdgcn_exp2f(s1[r+3]);
            sum0 += pv[0][r+0] + pv[1][r+0];
            sum1 += pv[0][r+1] + pv[1][r+1];
            sum2 += pv[0][r+2] + pv[1][r+2];
            sum3 += pv[0][r+3] + pv[1][r+3];
        }

        // ---- assemble PV A-frags in registers via permlane32_swap ----
        half8 pa[4];
        #pragma unroll
        for (int sl = 0; sl < 4; ++sl) {
            const int blk = sl >> 1, rb = (sl & 1) * 8;
            unsigned A0 = pk2(pv[blk][rb + 0], pv[blk][rb + 1]);
            unsigned A1 = pk2(pv[blk][rb + 2], pv[blk][rb + 3]);
            unsigned B0 = pk2(pv[blk][rb + 4], pv[blk][rb + 5]);
            unsigned B1 = pk2(pv[blk][rb + 6], pv[blk][rb + 7]);
            asm volatile("v_permlane32_swap_b32 %0, %1" : "+v"(A0), "+v"(B0));
            asm volatile("v_permlane32_swap_b32 %0, %1" : "+v"(A1), "+v"(B1));
            union { unsigned u[4]; half8 h; } uu;
            uu.u[0] = A0; uu.u[1] = A1; uu.u[2] = B0; uu.u[3] = B1;
            pa[sl] = uu.h;
        }

        // ---- PV ----
        __builtin_amdgcn_s_setprio(1);
        #pragma unroll
        for (int sl = 0; sl < 4; ++sl) {
            const half8 v0 = *(const half8*)((const char*)&Vs[cur][0]
                             + sl * 2048 + lq * 32 + lh * 16);
            const half8 v1 = *(const half8*)((const char*)&Vs[cur][0]
                             + sl * 2048 + (32 + lq) * 32 + lh * 16);
            o0 = MFMA32(pa[sl], v0, o0);
            o1 = MFMA32(pa[sl], v1, o1);
        }
        __builtin_amdgcn_s_setprio(0);

        __syncthreads();
        cur ^= 1;
    }

    // ---- cross-half combine of the row sum (lane (lq,0) <-> (lq,1)) ----
    const float partial = (sum0 + sum1) + (sum2 + sum3);
    {
        unsigned X = __builtin_bit_cast(unsigned, partial);
        unsigned Y = __builtin_bit_cast(unsigned, partial);
        asm volatile("v_permlane32_swap_b32 %0, %1" : "+v"(X), "+v"(Y));
        const float other = lh ? __builtin_bit_cast(float, X)
                               : __builtin_bit_cast(float, Y);
        const float full = partial + other;
        const float inv = 1.0f / full;

        const int b = bh >> 4, h = bh & 15;
        #pragma unroll
        for (int r = 0; r < 16; ++r) {
            const int rowq = (r & 3) + 8 * (r >> 2) + 4 * lh;
            const float li = __shfl(inv, rowq, 64);
            const int n = q0 + w * 32 + rowq;
            _Float16* dst = ao + ((size_t)(b * N_ + n)) * C_ + h * D_;
            dst[lq]      = (_Float16)(o0[r] * li);
            dst[32 + lq] = (_Float16)(o1[r] * li);
        }
    }
}

// ---------------------------------------------------------------------------
extern "C" void kernel_launch(void* const* d_in, const int* in_sizes, int n_in,
                              void* d_out, int out_size, void* d_ws, size_t ws_size,
                              hipStream_t stream) {
    const float* x      = (const float*)d_in[0];
    const float* w_qkv  = (const float*)d_in[1];
    const float* b_qkv  = (const float*)d_in[2];
    const float* w_proj = (const float*)d_in[3];
    const float* b_proj = (const float*)d_in[4];
    float* out = (float*)d_out;

    char* wsb = (char*)d_ws;
    const size_t MB = 1u << 20;
    _Float16* xh  = (_Float16*)(wsb + 0);        // 8 MB [4096][1024]
    _Float16* wqT = (_Float16*)(wsb + 8*MB);     // 6 MB [3072][1024]
    _Float16* wpT = (_Float16*)(wsb + 14*MB);    // 2 MB [1024][1024]
    _Float16* qb  = (_Float16*)(wsb + 16*MB);    // 8 MB [32][2048][64]
    _Float16* kb  = (_Float16*)(wsb + 24*MB);    // 8 MB
    _Float16* vtb = (_Float16*)(wsb + 32*MB);    // 8 MB [32][64][2048]
    _Float16* ao  = (_Float16*)(wsb + 0);        // alias xh (dead after QKV gemm)

    prep_kernel<<<6144, 256, 0, stream>>>(x, w_qkv, w_proj, xh, wqT, wpT);

    gemm_s_kernel<0><<<dim3(QKV_N/128, M_TOT/128), 256, 0, stream>>>(
        xh, wqT, b_qkv, qb, kb, vtb, nullptr);

    attn_mfma_kernel<<<512, 256, 0, stream>>>(qb, kb, vtb, ao);

    gemm_s_kernel<1><<<dim3(C_/128, M_TOT/128), 256, 0, stream>>>(
        ao, wpT, b_proj, nullptr, nullptr, nullptr, out);
}